// Round 1
// baseline (966.187 us; speedup 1.0000x reference)
//
#include <hip/hip_runtime.h>

#define NN 50000
#define NE 1600000
#define EP (NE + NN)          // edges + self loops = 1,650,000
#define D 128
#define H 4
#define NEG 0.2f
#define LN_EPS 1e-5f

static __device__ __forceinline__ float leakyf(float v) { return v > 0.f ? v : NEG * v; }

// ------------------------- CSR build -------------------------
__global__ void k_zero(int* __restrict__ deg, int* __restrict__ cur) {
    int i = blockIdx.x * blockDim.x + threadIdx.x;
    if (i < NN) { deg[i] = 0; cur[i] = 0; }
}

__global__ void k_count(const int* __restrict__ ei, int* __restrict__ deg) {
    int k = blockIdx.x * blockDim.x + threadIdx.x;
    if (k >= EP) return;
    int dst = (k < NE) ? ei[NE + k] : (k - NE);
    atomicAdd(&deg[dst], 1);
}

#define SCAN_B 512
__global__ void k_scan1(const int* __restrict__ deg, int* __restrict__ stmp, int* __restrict__ bsum) {
    __shared__ int sm[SCAN_B];
    int i = blockIdx.x * SCAN_B + threadIdx.x;
    sm[threadIdx.x] = (i < NN) ? deg[i] : 0;
    __syncthreads();
    for (int off = 1; off < SCAN_B; off <<= 1) {
        int t = (threadIdx.x >= off) ? sm[threadIdx.x - off] : 0;
        __syncthreads();
        sm[threadIdx.x] += t;
        __syncthreads();
    }
    if (i < NN) stmp[i] = sm[threadIdx.x];
    if (threadIdx.x == SCAN_B - 1) bsum[blockIdx.x] = sm[SCAN_B - 1];
}

__global__ void k_scan2(int* __restrict__ bsum, int nb) {
    __shared__ int sm[256];
    int v = (threadIdx.x < nb) ? bsum[threadIdx.x] : 0;
    sm[threadIdx.x] = v;
    __syncthreads();
    for (int off = 1; off < 256; off <<= 1) {
        int t = (threadIdx.x >= off) ? sm[threadIdx.x - off] : 0;
        __syncthreads();
        sm[threadIdx.x] += t;
        __syncthreads();
    }
    if (threadIdx.x < nb) bsum[threadIdx.x] = sm[threadIdx.x];
}

__global__ void k_scan3(const int* __restrict__ stmp, const int* __restrict__ bsum, int* __restrict__ rowptr) {
    int i = blockIdx.x * SCAN_B + threadIdx.x;
    if (i >= NN) return;
    int add = (blockIdx.x > 0) ? bsum[blockIdx.x - 1] : 0;
    rowptr[i + 1] = stmp[i] + add;
    if (i == 0) rowptr[0] = 0;
}

__global__ void k_fill(const int* __restrict__ ei, const int* __restrict__ rowptr,
                       int* __restrict__ cur, int* __restrict__ csr) {
    int k = blockIdx.x * blockDim.x + threadIdx.x;
    if (k >= EP) return;
    int src, dst;
    if (k < NE) { src = ei[k]; dst = ei[NE + k]; }
    else        { src = k - NE; dst = src; }
    int pos = rowptr[dst] + atomicAdd(&cur[dst], 1);
    csr[pos] = src;
}

// ------------------------- input projection -------------------------
__global__ void k_in(const float* __restrict__ x, const float* __restrict__ w,
                     const float* __restrict__ b, float* __restrict__ h) {
    int t = blockIdx.x * blockDim.x + threadIdx.x;
    if (t >= NN * D) return;
    int n = t >> 7, d = t & 127;
    const float* xr = x + n * 5;
    float acc = b[d];
#pragma unroll
    for (int k = 0; k < 5; k++) acc = fmaf(xr[k], w[k * D + d], acc);
    h[t] = acc;
}

// ------------------------- GEMM xh = h @ W (128x128) -------------------------
#define NPB 16
__global__ __launch_bounds__(256) void k_gemm(const float* __restrict__ h,
                                              const float* __restrict__ W,
                                              float* __restrict__ xh) {
    __shared__ float sW[64 * D];   // 32 KB (one K-half of W)
    __shared__ float sH[NPB * D];  // 8 KB
    int tid = threadIdx.x;
    int nbase = blockIdx.x * NPB;
    for (int i = tid; i < NPB * D; i += 256) {
        int n = nbase + (i >> 7);
        sH[i] = (n < NN) ? h[(size_t)n * D + (i & 127)] : 0.f;
    }
    int d = tid & 127;
    int slot = tid >> 7;  // 0/1 : which 8-node group
    float acc[NPB / 2];
#pragma unroll
    for (int j = 0; j < NPB / 2; j++) acc[j] = 0.f;
#pragma unroll
    for (int p = 0; p < 2; p++) {
        __syncthreads();
        for (int i = tid; i < 64 * D; i += 256) sW[i] = W[p * 64 * D + i];
        __syncthreads();
#pragma unroll 4
        for (int kk = 0; kk < 64; kk++) {
            float wv = sW[kk * D + d];
#pragma unroll
            for (int j = 0; j < NPB / 2; j++)
                acc[j] = fmaf(sH[(slot * (NPB / 2) + j) * D + p * 64 + kk], wv, acc[j]);
        }
    }
#pragma unroll
    for (int j = 0; j < NPB / 2; j++) {
        int n = nbase + slot * (NPB / 2) + j;
        if (n < NN) xh[(size_t)n * D + d] = acc[j];
    }
}

// ------------------------- attention logits per node -------------------------
__global__ void k_al(const float* __restrict__ xh, const float* __restrict__ asrc,
                     const float* __restrict__ adst, float* __restrict__ als,
                     float* __restrict__ ald) {
    int t = blockIdx.x * blockDim.x + threadIdx.x;
    if (t >= NN * D) return;
    int n = t >> 7, d = t & 127;
    float v = xh[t];
    float ps = v * asrc[d];
    float pd = v * adst[d];
#pragma unroll
    for (int off = 16; off; off >>= 1) {
        ps += __shfl_xor(ps, off, 32);
        pd += __shfl_xor(pd, off, 32);
    }
    if ((d & 31) == 0) {
        int hh = d >> 5;
        als[n * H + hh] = ps;
        ald[n * H + hh] = pd;
    }
}

// ------------------------- fused aggregation + bias + LN + relu + residual ----
__global__ __launch_bounds__(256) void k_agg(const float* __restrict__ xh,
                                             const float* __restrict__ als,
                                             const float* __restrict__ ald,
                                             const int* __restrict__ rowptr,
                                             const int* __restrict__ csr,
                                             const float* __restrict__ cb,
                                             const float* __restrict__ gamma,
                                             const float* __restrict__ beta,
                                             float* __restrict__ h, int do_relu) {
    int node = blockIdx.x * 4 + (threadIdx.x >> 6);
    if (node >= NN) return;
    int lane = threadIdx.x & 63;
    int start = rowptr[node], end = rowptr[node + 1];

    float ad0 = ald[node * H + 0], ad1 = ald[node * H + 1];
    float ad2 = ald[node * H + 2], ad3 = ald[node * H + 3];

    // pass 1: segment max per head (lane-parallel over edges)
    float m0 = -1e30f, m1 = -1e30f, m2 = -1e30f, m3 = -1e30f;
    for (int e = start + lane; e < end; e += 64) {
        int s = csr[e];
        const float* ap = als + s * H;
        m0 = fmaxf(m0, leakyf(ap[0] + ad0));
        m1 = fmaxf(m1, leakyf(ap[1] + ad1));
        m2 = fmaxf(m2, leakyf(ap[2] + ad2));
        m3 = fmaxf(m3, leakyf(ap[3] + ad3));
    }
#pragma unroll
    for (int off = 32; off; off >>= 1) {
        m0 = fmaxf(m0, __shfl_xor(m0, off));
        m1 = fmaxf(m1, __shfl_xor(m1, off));
        m2 = fmaxf(m2, __shfl_xor(m2, off));
        m3 = fmaxf(m3, __shfl_xor(m3, off));
    }

    // pass 2: serial over edges, lanes over dims (lane -> dims lane, lane+64)
    int hsel = lane >> 5;                    // 0 or 1
    int h0 = hsel;                           // head for dim `lane`
    int h1 = 2 + hsel;                       // head for dim `lane+64`
    float mA = hsel ? m1 : m0;
    float mB = hsel ? m3 : m2;
    float adA = hsel ? ad1 : ad0;
    float adB = hsel ? ad3 : ad2;

    float acc0 = 0.f, acc1 = 0.f, den0 = 0.f, den1 = 0.f;
    for (int e = start; e < end; ++e) {
        int s = csr[e];
        float eA = __expf(leakyf(als[s * H + h0] + adA) - mA);
        float eB = __expf(leakyf(als[s * H + h1] + adB) - mB);
        den0 += eA;
        den1 += eB;
        const float* xr = xh + (size_t)s * D;
        acc0 = fmaf(eA, xr[lane], acc0);
        acc1 = fmaf(eB, xr[lane + 64], acc1);
    }

    float o0 = acc0 / (den0 + 1e-16f) + cb[lane];
    float o1 = acc1 / (den1 + 1e-16f) + cb[lane + 64];

    // LayerNorm over 128 dims (wave reduction)
    float s = o0 + o1;
#pragma unroll
    for (int off = 32; off; off >>= 1) s += __shfl_xor(s, off);
    float mean = s * (1.f / 128.f);
    float c0 = o0 - mean, c1 = o1 - mean;
    float v = c0 * c0 + c1 * c1;
#pragma unroll
    for (int off = 32; off; off >>= 1) v += __shfl_xor(v, off);
    float inv = rsqrtf(v * (1.f / 128.f) + LN_EPS);
    float r0 = c0 * inv * gamma[lane] + beta[lane];
    float r1 = c1 * inv * gamma[lane + 64] + beta[lane + 64];
    if (do_relu) { r0 = fmaxf(r0, 0.f); r1 = fmaxf(r1, 0.f); }
    h[(size_t)node * D + lane] += r0;
    h[(size_t)node * D + lane + 64] += r1;
}

// ------------------------- launch -------------------------
extern "C" void kernel_launch(void* const* d_in, const int* in_sizes, int n_in,
                              void* d_out, int out_size, void* d_ws, size_t ws_size,
                              hipStream_t stream) {
    const float* x    = (const float*)d_in[0];
    const float* w_in = (const float*)d_in[1];
    const float* b_in = (const float*)d_in[2];
    const int*   ei   = (const int*)d_in[21];
    float* h = (float*)d_out;

    char* w = (char*)d_ws;
    int* deg    = (int*)w;  w += (size_t)NN * 4;
    int* cur    = (int*)w;  w += (size_t)NN * 4;
    int* stmp   = (int*)w;  w += (size_t)NN * 4;
    int* bsum   = (int*)w;  w += 1024;
    int* rowptr = (int*)w;  w += (size_t)(NN + 4) * 4;
    int* csr    = (int*)w;  w += (size_t)EP * 4;
    float* xh   = (float*)w; w += (size_t)NN * D * 4;
    float* als  = (float*)w; w += (size_t)NN * H * 4;
    float* ald  = (float*)w; w += (size_t)NN * H * 4;

    int nbScan = (NN + SCAN_B - 1) / SCAN_B;  // 98

    k_zero<<<(NN + 255) / 256, 256, 0, stream>>>(deg, cur);
    k_count<<<(EP + 255) / 256, 256, 0, stream>>>(ei, deg);
    k_scan1<<<nbScan, SCAN_B, 0, stream>>>(deg, stmp, bsum);
    k_scan2<<<1, 256, 0, stream>>>(bsum, nbScan);
    k_scan3<<<nbScan, SCAN_B, 0, stream>>>(stmp, bsum, rowptr);
    k_fill<<<(EP + 255) / 256, 256, 0, stream>>>(ei, rowptr, cur, csr);

    k_in<<<(NN * D) / 256, 256, 0, stream>>>(x, w_in, b_in, h);

    for (int L = 0; L < 3; ++L) {
        const float* W    = (const float*)d_in[3 + 6 * L];
        const float* asrc = (const float*)d_in[4 + 6 * L];
        const float* adst = (const float*)d_in[5 + 6 * L];
        const float* cb   = (const float*)d_in[6 + 6 * L];
        const float* g    = (const float*)d_in[7 + 6 * L];
        const float* lb   = (const float*)d_in[8 + 6 * L];
        k_gemm<<<NN / NPB, 256, 0, stream>>>(h, W, xh);
        k_al<<<(NN * D) / 256, 256, 0, stream>>>(xh, asrc, adst, als, ald);
        k_agg<<<NN / 4, 256, 0, stream>>>(xh, als, ald, rowptr, csr, cb, g, lb, h, L < 2 ? 1 : 0);
    }
}

// Round 2
// 703.429 us; speedup vs baseline: 1.3735x; 1.3735x over previous
//
#include <hip/hip_runtime.h>
#include <hip/hip_fp16.h>

#define NN 50000
#define NE 1600000
#define EP (NE + NN)          // edges + self loops = 1,650,000
#define D 128
#define H 4
#define NEG 0.2f
#define LN_EPS 1e-5f

static __device__ __forceinline__ float leakyf(float v) { return v > 0.f ? v : NEG * v; }

// ------------------------- CSR build -------------------------
__global__ void k_zero(int* __restrict__ deg, int* __restrict__ cur) {
    int i = blockIdx.x * blockDim.x + threadIdx.x;
    if (i < NN) { deg[i] = 0; cur[i] = 0; }
}

__global__ void k_count(const int* __restrict__ ei, int* __restrict__ deg) {
    int k = blockIdx.x * blockDim.x + threadIdx.x;
    if (k >= EP) return;
    int dst = (k < NE) ? ei[NE + k] : (k - NE);
    atomicAdd(&deg[dst], 1);
}

#define SCAN_B 512
__global__ void k_scan1(const int* __restrict__ deg, int* __restrict__ stmp, int* __restrict__ bsum) {
    __shared__ int sm[SCAN_B];
    int i = blockIdx.x * SCAN_B + threadIdx.x;
    sm[threadIdx.x] = (i < NN) ? deg[i] : 0;
    __syncthreads();
    for (int off = 1; off < SCAN_B; off <<= 1) {
        int t = (threadIdx.x >= off) ? sm[threadIdx.x - off] : 0;
        __syncthreads();
        sm[threadIdx.x] += t;
        __syncthreads();
    }
    if (i < NN) stmp[i] = sm[threadIdx.x];
    if (threadIdx.x == SCAN_B - 1) bsum[blockIdx.x] = sm[SCAN_B - 1];
}

__global__ void k_scan2(int* __restrict__ bsum, int nb) {
    __shared__ int sm[256];
    int v = (threadIdx.x < nb) ? bsum[threadIdx.x] : 0;
    sm[threadIdx.x] = v;
    __syncthreads();
    for (int off = 1; off < 256; off <<= 1) {
        int t = (threadIdx.x >= off) ? sm[threadIdx.x - off] : 0;
        __syncthreads();
        sm[threadIdx.x] += t;
        __syncthreads();
    }
    if (threadIdx.x < nb) bsum[threadIdx.x] = sm[threadIdx.x];
}

__global__ void k_scan3(const int* __restrict__ stmp, const int* __restrict__ bsum, int* __restrict__ rowptr) {
    int i = blockIdx.x * SCAN_B + threadIdx.x;
    if (i >= NN) return;
    int add = (blockIdx.x > 0) ? bsum[blockIdx.x - 1] : 0;
    rowptr[i + 1] = stmp[i] + add;
    if (i == 0) rowptr[0] = 0;
}

__global__ void k_fill(const int* __restrict__ ei, const int* __restrict__ rowptr,
                       int* __restrict__ cur, int* __restrict__ csr) {
    int k = blockIdx.x * blockDim.x + threadIdx.x;
    if (k >= EP) return;
    int src, dst;
    if (k < NE) { src = ei[k]; dst = ei[NE + k]; }
    else        { src = k - NE; dst = src; }
    int pos = rowptr[dst] + atomicAdd(&cur[dst], 1);
    csr[pos] = src;
}

// ------------------------- input projection -------------------------
__global__ void k_in(const float* __restrict__ x, const float* __restrict__ w,
                     const float* __restrict__ b, float* __restrict__ h) {
    int t = blockIdx.x * blockDim.x + threadIdx.x;
    if (t >= NN * D) return;
    int n = t >> 7, d = t & 127;
    const float* xr = x + n * 5;
    float acc = b[d];
#pragma unroll
    for (int k = 0; k < 5; k++) acc = fmaf(xr[k], w[k * D + d], acc);
    h[t] = acc;
}

// --------- GEMM xh = h @ W (fp16 out) + fused attention-logit epilogue ------
#define NPB 16
__global__ __launch_bounds__(256) void k_gemm(const float* __restrict__ h,
                                              const float* __restrict__ W,
                                              const float* __restrict__ asrc,
                                              const float* __restrict__ adst,
                                              __half* __restrict__ xh,
                                              float* __restrict__ als,
                                              float* __restrict__ ald) {
    __shared__ float sW[64 * D];     // 32 KB (one K-half of W)
    __shared__ float sHt[D * NPB];   // 8 KB, transposed [k][n]
    int tid = threadIdx.x;
    int nbase = blockIdx.x * NPB;
    for (int i = tid; i < NPB * D; i += 256) {
        int n = nbase + (i >> 7);
        float v = (n < NN) ? h[(size_t)n * D + (i & 127)] : 0.f;
        sHt[(i & 127) * NPB + (i >> 7)] = v;
    }
    int d = tid & 127;
    int slot = tid >> 7;  // 0/1 : which 8-node group
    float acc[8];
#pragma unroll
    for (int j = 0; j < 8; j++) acc[j] = 0.f;
#pragma unroll
    for (int p = 0; p < 2; p++) {
        __syncthreads();
        for (int i = tid; i < 64 * D; i += 256) sW[i] = W[p * 64 * D + i];
        __syncthreads();
#pragma unroll 4
        for (int kk = 0; kk < 64; kk++) {
            float wv = sW[kk * D + d];
            const float4* hp = (const float4*)&sHt[(p * 64 + kk) * NPB + slot * 8];
            float4 a = hp[0], b = hp[1];
            acc[0] = fmaf(a.x, wv, acc[0]);
            acc[1] = fmaf(a.y, wv, acc[1]);
            acc[2] = fmaf(a.z, wv, acc[2]);
            acc[3] = fmaf(a.w, wv, acc[3]);
            acc[4] = fmaf(b.x, wv, acc[4]);
            acc[5] = fmaf(b.y, wv, acc[5]);
            acc[6] = fmaf(b.z, wv, acc[6]);
            acc[7] = fmaf(b.w, wv, acc[7]);
        }
    }
    float as = asrc[d], adv = adst[d];
    int head = d >> 5;
#pragma unroll
    for (int j = 0; j < 8; j++) {
        int n = nbase + slot * 8 + j;
        if (n >= NN) break;
        xh[(size_t)n * D + d] = __float2half(acc[j]);
        float ps = acc[j] * as;
        float pd = acc[j] * adv;
#pragma unroll
        for (int off = 16; off; off >>= 1) {
            ps += __shfl_xor(ps, off, 32);
            pd += __shfl_xor(pd, off, 32);
        }
        if ((d & 31) == 0) {
            als[n * H + head] = ps;
            ald[n * H + head] = pd;
        }
    }
}

// ------------------------- fused aggregation + bias + LN + relu + residual ----
__global__ __launch_bounds__(256) void k_agg(const __half* __restrict__ xh,
                                             const float* __restrict__ als,
                                             const float* __restrict__ ald,
                                             const int* __restrict__ rowptr,
                                             const int* __restrict__ csr,
                                             const float* __restrict__ cb,
                                             const float* __restrict__ gamma,
                                             const float* __restrict__ beta,
                                             float* __restrict__ h, int do_relu) {
    int node = blockIdx.x * 4 + (threadIdx.x >> 6);
    if (node >= NN) return;
    int lane = threadIdx.x & 63;
    int start = rowptr[node], end = rowptr[node + 1];

    float4 adr = *(const float4*)&ald[node * H];

    // pass 1: segment max per head (lane-parallel over edges)
    float m0 = -1e30f, m1 = -1e30f, m2 = -1e30f, m3 = -1e30f;
    for (int e = start + lane; e < end; e += 64) {
        int s = csr[e];
        float4 ap = *(const float4*)&als[s * H];
        m0 = fmaxf(m0, leakyf(ap.x + adr.x));
        m1 = fmaxf(m1, leakyf(ap.y + adr.y));
        m2 = fmaxf(m2, leakyf(ap.z + adr.z));
        m3 = fmaxf(m3, leakyf(ap.w + adr.w));
    }
#pragma unroll
    for (int off = 32; off; off >>= 1) {
        m0 = fmaxf(m0, __shfl_xor(m0, off));
        m1 = fmaxf(m1, __shfl_xor(m1, off));
        m2 = fmaxf(m2, __shfl_xor(m2, off));
        m3 = fmaxf(m3, __shfl_xor(m3, off));
    }

    // pass 2: serial over edges; lane owns dims (2*lane, 2*lane+1) -> head lane>>4
    int hh = lane >> 4;
    float mH  = hh == 0 ? m0 : (hh == 1 ? m1 : (hh == 2 ? m2 : m3));
    float adH = hh == 0 ? adr.x : (hh == 1 ? adr.y : (hh == 2 ? adr.z : adr.w));

    const __half2* xh2 = (const __half2*)xh;
    float acc0 = 0.f, acc1 = 0.f, den = 0.f;
#pragma unroll 2
    for (int e = start; e < end; ++e) {
        int s = csr[e];
        float ev = __expf(leakyf(als[s * H + hh] + adH) - mH);
        den += ev;
        float2 f = __half22float2(xh2[(size_t)s * 64 + lane]);
        acc0 = fmaf(ev, f.x, acc0);
        acc1 = fmaf(ev, f.y, acc1);
    }

    float2 cb2 = ((const float2*)cb)[lane];
    float inv_den = 1.f / (den + 1e-16f);
    float o0 = acc0 * inv_den + cb2.x;
    float o1 = acc1 * inv_den + cb2.y;

    // LayerNorm over 128 dims (wave reduction)
    float s = o0 + o1;
#pragma unroll
    for (int off = 32; off; off >>= 1) s += __shfl_xor(s, off);
    float mean = s * (1.f / 128.f);
    float c0 = o0 - mean, c1 = o1 - mean;
    float v = c0 * c0 + c1 * c1;
#pragma unroll
    for (int off = 32; off; off >>= 1) v += __shfl_xor(v, off);
    float inv = rsqrtf(v * (1.f / 128.f) + LN_EPS);
    float2 g2 = ((const float2*)gamma)[lane];
    float2 b2 = ((const float2*)beta)[lane];
    float r0 = c0 * inv * g2.x + b2.x;
    float r1 = c1 * inv * g2.y + b2.y;
    if (do_relu) { r0 = fmaxf(r0, 0.f); r1 = fmaxf(r1, 0.f); }
    float2* hp = (float2*)&h[(size_t)node * D + 2 * lane];
    float2 hv = *hp;
    hv.x += r0;
    hv.y += r1;
    *hp = hv;
}

// ------------------------- launch -------------------------
extern "C" void kernel_launch(void* const* d_in, const int* in_sizes, int n_in,
                              void* d_out, int out_size, void* d_ws, size_t ws_size,
                              hipStream_t stream) {
    const float* x    = (const float*)d_in[0];
    const float* w_in = (const float*)d_in[1];
    const float* b_in = (const float*)d_in[2];
    const int*   ei   = (const int*)d_in[21];
    float* h = (float*)d_out;

    char* w = (char*)d_ws;
    int* deg    = (int*)w;  w += (size_t)NN * 4;
    int* cur    = (int*)w;  w += (size_t)NN * 4;
    int* stmp   = (int*)w;  w += (size_t)NN * 4;
    int* bsum   = (int*)w;  w += 1024;
    int* rowptr = (int*)w;  w += (size_t)(NN + 4) * 4;
    int* csr    = (int*)w;  w += (size_t)EP * 4;
    __half* xh  = (__half*)w; w += (size_t)NN * D * 2;
    float* als  = (float*)w; w += (size_t)NN * H * 4;
    float* ald  = (float*)w; w += (size_t)NN * H * 4;

    int nbScan = (NN + SCAN_B - 1) / SCAN_B;  // 98

    k_zero<<<(NN + 255) / 256, 256, 0, stream>>>(deg, cur);
    k_count<<<(EP + 255) / 256, 256, 0, stream>>>(ei, deg);
    k_scan1<<<nbScan, SCAN_B, 0, stream>>>(deg, stmp, bsum);
    k_scan2<<<1, 256, 0, stream>>>(bsum, nbScan);
    k_scan3<<<nbScan, SCAN_B, 0, stream>>>(stmp, bsum, rowptr);
    k_fill<<<(EP + 255) / 256, 256, 0, stream>>>(ei, rowptr, cur, csr);

    k_in<<<(NN * D) / 256, 256, 0, stream>>>(x, w_in, b_in, h);

    for (int L = 0; L < 3; ++L) {
        const float* W    = (const float*)d_in[3 + 6 * L];
        const float* asrc = (const float*)d_in[4 + 6 * L];
        const float* adst = (const float*)d_in[5 + 6 * L];
        const float* cb   = (const float*)d_in[6 + 6 * L];
        const float* g    = (const float*)d_in[7 + 6 * L];
        const float* lb   = (const float*)d_in[8 + 6 * L];
        k_gemm<<<NN / NPB, 256, 0, stream>>>(h, W, asrc, adst, xh, als, ald);
        k_agg<<<NN / 4, 256, 0, stream>>>(xh, als, ald, rowptr, csr, cb, g, lb, h, L < 2 ? 1 : 0);
    }
}

// Round 3
// 568.836 us; speedup vs baseline: 1.6985x; 1.2366x over previous
//
#include <hip/hip_runtime.h>

#define NN 50000
#define NE 1600000
#define EP (NE + NN)          // edges + self loops = 1,650,000
#define D 128
#define H 4
#define NEG 0.2f
#define LN_EPS 1e-5f

typedef _Float16 f16;
typedef _Float16 half8 __attribute__((ext_vector_type(8)));
typedef _Float16 half2v __attribute__((ext_vector_type(2)));
typedef float f32x4v __attribute__((ext_vector_type(4)));

static __device__ __forceinline__ float leakyf(float v) { return v > 0.f ? v : NEG * v; }

// monotone float<->int key for atomicMax-based float max
static __device__ __forceinline__ int fkey(float v) {
    int b = __float_as_int(v);
    return b >= 0 ? b : (b ^ 0x7fffffff);
}
static __device__ __forceinline__ float fdec(int k) {
    return __int_as_float(k >= 0 ? k : (k ^ 0x7fffffff));
}
#define NEG_INF_KEY 0x807fffff

// ------------------------- CSR build -------------------------
__global__ void k_zero(int* __restrict__ deg, int* __restrict__ cur, int* __restrict__ gmaxk) {
    int i = blockIdx.x * blockDim.x + threadIdx.x;
    if (i < NN) { deg[i] = 0; cur[i] = 0; }
    if (i < 12) gmaxk[i] = NEG_INF_KEY;
}

__global__ void k_count(const int* __restrict__ ei, int* __restrict__ deg) {
    int k = blockIdx.x * blockDim.x + threadIdx.x;
    if (k >= EP) return;
    int dst = (k < NE) ? ei[NE + k] : (k - NE);
    atomicAdd(&deg[dst], 1);
}

#define SCAN_B 512
__global__ void k_scan1(const int* __restrict__ deg, int* __restrict__ stmp, int* __restrict__ bsum) {
    __shared__ int sm[SCAN_B];
    int i = blockIdx.x * SCAN_B + threadIdx.x;
    sm[threadIdx.x] = (i < NN) ? deg[i] : 0;
    __syncthreads();
    for (int off = 1; off < SCAN_B; off <<= 1) {
        int t = (threadIdx.x >= off) ? sm[threadIdx.x - off] : 0;
        __syncthreads();
        sm[threadIdx.x] += t;
        __syncthreads();
    }
    if (i < NN) stmp[i] = sm[threadIdx.x];
    if (threadIdx.x == SCAN_B - 1) bsum[blockIdx.x] = sm[SCAN_B - 1];
}

__global__ void k_scan2(int* __restrict__ bsum, int nb) {
    __shared__ int sm[256];
    int v = (threadIdx.x < nb) ? bsum[threadIdx.x] : 0;
    sm[threadIdx.x] = v;
    __syncthreads();
    for (int off = 1; off < 256; off <<= 1) {
        int t = (threadIdx.x >= off) ? sm[threadIdx.x - off] : 0;
        __syncthreads();
        sm[threadIdx.x] += t;
        __syncthreads();
    }
    if (threadIdx.x < nb) bsum[threadIdx.x] = sm[threadIdx.x];
}

__global__ void k_scan3(const int* __restrict__ stmp, const int* __restrict__ bsum, int* __restrict__ rowptr) {
    int i = blockIdx.x * SCAN_B + threadIdx.x;
    if (i >= NN) return;
    int add = (blockIdx.x > 0) ? bsum[blockIdx.x - 1] : 0;
    rowptr[i + 1] = stmp[i] + add;
    if (i == 0) rowptr[0] = 0;
}

__global__ void k_fill(const int* __restrict__ ei, const int* __restrict__ rowptr,
                       int* __restrict__ cur, int* __restrict__ csr) {
    int k = blockIdx.x * blockDim.x + threadIdx.x;
    if (k >= EP) return;
    int src, dst;
    if (k < NE) { src = ei[k]; dst = ei[NE + k]; }
    else        { src = k - NE; dst = src; }
    int pos = rowptr[dst] + atomicAdd(&cur[dst], 1);
    csr[pos] = src;
}

// ------------------------- W -> fp16 transposed [col][k] -------------------------
__global__ void k_cvtw(const float* __restrict__ w0, const float* __restrict__ w1,
                       const float* __restrict__ w2, f16* __restrict__ wt) {
    int t = blockIdx.x * blockDim.x + threadIdx.x;
    if (t >= 3 * D * D) return;
    int l = t / (D * D), rem = t % (D * D);
    int k = rem >> 7, c = rem & 127;
    const float* w = (l == 0) ? w0 : (l == 1) ? w1 : w2;
    wt[l * D * D + c * D + k] = (f16)w[rem];
}

// ------------------------- input projection -------------------------
__global__ void k_in(const float* __restrict__ x, const float* __restrict__ w,
                     const float* __restrict__ b, float* __restrict__ h,
                     f16* __restrict__ h16) {
    int t = blockIdx.x * blockDim.x + threadIdx.x;
    if (t >= NN * D) return;
    int n = t >> 7, d = t & 127;
    const float* xr = x + n * 5;
    float acc = b[d];
#pragma unroll
    for (int k = 0; k < 5; k++) acc = fmaf(xr[k], w[k * D + d], acc);
    h[t] = acc;
    h16[t] = (f16)acc;
}

// --------- MFMA GEMM xh = h16 @ W16 + fused attention logits + global max ------
__global__ __launch_bounds__(256) void k_gemm(const f16* __restrict__ h16,
                                              const f16* __restrict__ wt,
                                              const float* __restrict__ asrc,
                                              const float* __restrict__ adst,
                                              f16* __restrict__ xh,
                                              float* __restrict__ als,
                                              float* __restrict__ ald,
                                              int* __restrict__ gmaxk) {
    __shared__ int sgk[4];
    if (threadIdx.x < 4) sgk[threadIdx.x] = NEG_INF_KEY;
    int wid = threadIdx.x >> 6;
    int lane = threadIdx.x & 63;
    int wbase = blockIdx.x * 64 + wid * 16;
    int r = lane & 15;        // A row within tile / B col within tile / D col
    int g = lane >> 4;        // k-group (loads) and row-group (D)

    int arow = wbase + r; if (arow >= NN) arow = NN - 1;
    const f16* abase = h16 + (size_t)arow * D + g * 8;

    f32x4v acc[8];
#pragma unroll
    for (int nt = 0; nt < 8; nt++) acc[nt] = (f32x4v){0.f, 0.f, 0.f, 0.f};

#pragma unroll
    for (int ks = 0; ks < 4; ks++) {
        half8 a = *(const half8*)(abase + ks * 32);
#pragma unroll
        for (int nt = 0; nt < 8; nt++) {
            half8 b = *(const half8*)(wt + (size_t)(nt * 16 + r) * D + ks * 32 + g * 8);
            acc[nt] = __builtin_amdgcn_mfma_f32_16x16x32_f16(a, b, acc[nt], 0, 0, 0);
        }
    }

    // attention vectors for this lane's columns
    float asv[8], adv[8];
#pragma unroll
    for (int nt = 0; nt < 8; nt++) {
        asv[nt] = asrc[nt * 16 + r];
        adv[nt] = adst[nt * 16 + r];
    }

    float wmax0 = -1e30f, wmax1 = -1e30f, wmax2 = -1e30f, wmax3 = -1e30f;
#pragma unroll
    for (int rg = 0; rg < 4; rg++) {
        int node = wbase + g * 4 + rg;
        bool ok = node < NN;
        float hs[4] = {0.f, 0.f, 0.f, 0.f};
        float hd[4] = {0.f, 0.f, 0.f, 0.f};
#pragma unroll
        for (int nt = 0; nt < 8; nt++) {
            float v = acc[nt][rg];
            if (ok) xh[(size_t)node * D + nt * 16 + r] = (f16)v;
            hs[nt >> 1] = fmaf(v, asv[nt], hs[nt >> 1]);
            hd[nt >> 1] = fmaf(v, adv[nt], hd[nt >> 1]);
        }
#pragma unroll
        for (int off = 1; off < 16; off <<= 1) {
#pragma unroll
            for (int hh = 0; hh < 4; hh++) {
                hs[hh] += __shfl_xor(hs[hh], off);
                hd[hh] += __shfl_xor(hd[hh], off);
            }
        }
        if (r == 0 && ok) {
#pragma unroll
            for (int hh = 0; hh < 4; hh++) {
                als[node * H + hh] = hs[hh];
                ald[node * H + hh] = hd[hh];
            }
        }
        // clamped rows duplicate a real node -> still a valid max contribution
        wmax0 = fmaxf(wmax0, hs[0]);
        wmax1 = fmaxf(wmax1, hs[1]);
        wmax2 = fmaxf(wmax2, hs[2]);
        wmax3 = fmaxf(wmax3, hs[3]);
    }
    // reduce across the 4 row-groups of the wave
#pragma unroll
    for (int off = 16; off < 64; off <<= 1) {
        wmax0 = fmaxf(wmax0, __shfl_xor(wmax0, off));
        wmax1 = fmaxf(wmax1, __shfl_xor(wmax1, off));
        wmax2 = fmaxf(wmax2, __shfl_xor(wmax2, off));
        wmax3 = fmaxf(wmax3, __shfl_xor(wmax3, off));
    }
    __syncthreads();
    if (lane == 0) {
        atomicMax(&sgk[0], fkey(wmax0));
        atomicMax(&sgk[1], fkey(wmax1));
        atomicMax(&sgk[2], fkey(wmax2));
        atomicMax(&sgk[3], fkey(wmax3));
    }
    __syncthreads();
    if (threadIdx.x < 4) atomicMax(&gmaxk[threadIdx.x], sgk[threadIdx.x]);
}

// ------------------------- fused aggregation + bias + LN + relu + residual ----
__global__ __launch_bounds__(256) void k_agg(const f16* __restrict__ xh,
                                             const float* __restrict__ als,
                                             const float* __restrict__ ald,
                                             const int* __restrict__ gmaxk,
                                             const int* __restrict__ rowptr,
                                             const int* __restrict__ csr,
                                             const float* __restrict__ cb,
                                             const float* __restrict__ gamma,
                                             const float* __restrict__ beta,
                                             float* __restrict__ h,
                                             f16* __restrict__ h16, int do_relu) {
    int node = blockIdx.x * 4 + (threadIdx.x >> 6);
    if (node >= NN) return;
    int lane = threadIdx.x & 63;
    int start = rowptr[node], end = rowptr[node + 1];

    float4 adr = *(const float4*)&ald[node * H];

    // lane owns dims (2*lane, 2*lane+1) -> head lane>>4
    int hh = lane >> 4;
    float adH = hh == 0 ? adr.x : (hh == 1 ? adr.y : (hh == 2 ? adr.z : adr.w));
    // upper bound on segment max: leaky is monotone, als <= gmax
    float mH = leakyf(fdec(gmaxk[hh]) + adH);

    const half2v* xh2 = (const half2v*)xh;
    float acc0 = 0.f, acc1 = 0.f, den = 0.f;
#pragma unroll 4
    for (int e = start; e < end; ++e) {
        int s = csr[e];
        float ev = __expf(leakyf(als[s * H + hh] + adH) - mH);
        den += ev;
        half2v p = xh2[(size_t)s * 64 + lane];
        acc0 = fmaf(ev, (float)p[0], acc0);
        acc1 = fmaf(ev, (float)p[1], acc1);
    }

    float2 cb2 = ((const float2*)cb)[lane];
    float inv_den = 1.f / (den + 1e-16f);
    float o0 = acc0 * inv_den + cb2.x;
    float o1 = acc1 * inv_den + cb2.y;

    // LayerNorm over 128 dims (wave reduction)
    float s = o0 + o1;
#pragma unroll
    for (int off = 32; off; off >>= 1) s += __shfl_xor(s, off);
    float mean = s * (1.f / 128.f);
    float c0 = o0 - mean, c1 = o1 - mean;
    float v = c0 * c0 + c1 * c1;
#pragma unroll
    for (int off = 32; off; off >>= 1) v += __shfl_xor(v, off);
    float inv = rsqrtf(v * (1.f / 128.f) + LN_EPS);
    float2 g2 = ((const float2*)gamma)[lane];
    float2 b2 = ((const float2*)beta)[lane];
    float r0 = c0 * inv * g2.x + b2.x;
    float r1 = c1 * inv * g2.y + b2.y;
    if (do_relu) { r0 = fmaxf(r0, 0.f); r1 = fmaxf(r1, 0.f); }
    float2* hp = (float2*)&h[(size_t)node * D + 2 * lane];
    float2 hv = *hp;
    hv.x += r0;
    hv.y += r1;
    *hp = hv;
    half2v h2; h2[0] = (f16)hv.x; h2[1] = (f16)hv.y;
    *(half2v*)&h16[(size_t)node * D + 2 * lane] = h2;
}

// ------------------------- launch -------------------------
extern "C" void kernel_launch(void* const* d_in, const int* in_sizes, int n_in,
                              void* d_out, int out_size, void* d_ws, size_t ws_size,
                              hipStream_t stream) {
    const float* x    = (const float*)d_in[0];
    const float* w_in = (const float*)d_in[1];
    const float* b_in = (const float*)d_in[2];
    const int*   ei   = (const int*)d_in[21];
    float* h = (float*)d_out;

    char* w = (char*)d_ws;
    int* deg    = (int*)w;  w += (size_t)NN * 4;
    int* cur    = (int*)w;  w += (size_t)NN * 4;
    int* stmp   = (int*)w;  w += (size_t)NN * 4;
    int* bsum   = (int*)w;  w += 1024;
    int* rowptr = (int*)w;  w += (size_t)(NN + 4) * 4;
    int* gmaxk  = (int*)w;  w += 64;
    int* csr    = (int*)w;  w += (size_t)EP * 4;
    f16* h16    = (f16*)w;  w += (size_t)NN * D * 2;
    f16* xh     = (f16*)w;  w += (size_t)NN * D * 2;
    f16* wt     = (f16*)w;  w += (size_t)3 * D * D * 2;
    float* als  = (float*)w; w += (size_t)NN * H * 4;
    float* ald  = (float*)w; w += (size_t)NN * H * 4;

    int nbScan = (NN + SCAN_B - 1) / SCAN_B;  // 98

    k_zero<<<(NN + 255) / 256, 256, 0, stream>>>(deg, cur, gmaxk);
    k_count<<<(EP + 255) / 256, 256, 0, stream>>>(ei, deg);
    k_scan1<<<nbScan, SCAN_B, 0, stream>>>(deg, stmp, bsum);
    k_scan2<<<1, 256, 0, stream>>>(bsum, nbScan);
    k_scan3<<<nbScan, SCAN_B, 0, stream>>>(stmp, bsum, rowptr);
    k_fill<<<(EP + 255) / 256, 256, 0, stream>>>(ei, rowptr, cur, csr);

    k_cvtw<<<(3 * D * D + 255) / 256, 256, 0, stream>>>(
        (const float*)d_in[3], (const float*)d_in[9], (const float*)d_in[15], wt);
    k_in<<<(NN * D) / 256, 256, 0, stream>>>(x, w_in, b_in, h, h16);

    for (int L = 0; L < 3; ++L) {
        const float* asrc = (const float*)d_in[4 + 6 * L];
        const float* adst = (const float*)d_in[5 + 6 * L];
        const float* cb   = (const float*)d_in[6 + 6 * L];
        const float* g    = (const float*)d_in[7 + 6 * L];
        const float* lb   = (const float*)d_in[8 + 6 * L];
        k_gemm<<<(NN + 63) / 64, 256, 0, stream>>>(h16, wt + (size_t)L * D * D,
                                                   asrc, adst, xh, als, ald, gmaxk + 4 * L);
        k_agg<<<NN / 4, 256, 0, stream>>>(xh, als, ald, gmaxk + 4 * L, rowptr, csr,
                                          cb, g, lb, h, h16, L < 2 ? 1 : 0);
    }
}